// Round 6
// baseline (71.051 us; speedup 1.0000x reference)
//
#include <hip/hip_runtime.h>
#include <math.h>

#define SD 39
#define BLOCK 256

__global__ __launch_bounds__(BLOCK)
__attribute__((amdgpu_waves_per_eu(2, 4)))   // LDS caps occupancy at 4 waves/SIMD
void qnet_kernel(
    const float* __restrict__ state,
    const float* __restrict__ ew1, const float* __restrict__ eb1,
    const float* __restrict__ ew2, const float* __restrict__ eb2,
    const float* __restrict__ ew3, const float* __restrict__ eb3,
    const float* __restrict__ qp,
    const float* __restrict__ dw1, const float* __restrict__ db1,
    const float* __restrict__ dw2, const float* __restrict__ db2,
    const float* __restrict__ dw3, const float* __restrict__ db3,
    float* __restrict__ out, int nrows_total)
{
    __shared__ __align__(16) float tile[BLOCK * SD];
    const int tid = threadIdx.x;
    const long long b0 = (long long)blockIdx.x * BLOCK;
    const int rows = (int)min((long long)BLOCK, (long long)nrows_total - b0);
    const float* src = state + b0 * SD;

    if (rows == BLOCK) {
        // 256*39 floats = 2496 float4; 256 threads -> 10 strided iters.
        const float4* s4 = (const float4*)src;
        float4* t4 = (float4*)tile;
        #pragma unroll 2
        for (int i = tid; i < (BLOCK * SD) / 4; i += BLOCK) t4[i] = s4[i];
    } else {
        for (int i = tid; i < rows * SD; i += BLOCK) tile[i] = src[i];
    }
    __syncthreads();

    if (tid >= rows) return;

    // Row -> registers via VOLATILE LDS reads. Volatile loads cannot be
    // duplicated or sunk into the FMA loops, so the 39 values must be
    // materialized ONCE and stay live in VGPRs across layer 1 (this is what
    // r52 builds got wrong: the compiler re-read LDS inside the loop and the
    // LDS pipe became the bottleneck at ~50% VALUBusy).
    volatile const float* vt = tile + tid * SD;
    float s[SD];
    #pragma unroll
    for (int i = 0; i < SD; i++) s[i] = vt[i];

    // ---- FUSED encoder layers 1+2: 39 -> 64 -> 32 ----
    // h1 never materialized; each h1 value folded straight into the 32
    // layer-2 accumulators. Peak live ~= s[39] + acc2[32] ~ 85 VGPRs.
    float acc2[32];
    #pragma unroll
    for (int o = 0; o < 32; o++) acc2[o] = eb2[o];

    #pragma unroll 4
    for (int o1 = 0; o1 < 64; o1++) {
        float a = eb1[o1];
        const float* w1 = ew1 + o1 * SD;       // uniform address -> s_load
        #pragma unroll
        for (int i = 0; i < SD; i++) a = fmaf(s[i], w1[i], a);
        a = fmaxf(a, 0.0f);
        #pragma unroll
        for (int o2 = 0; o2 < 32; o2++)
            acc2[o2] = fmaf(a, ew2[o2 * 64 + o1], acc2[o2]);
    }

    float h2[32];
    #pragma unroll
    for (int o = 0; o < 32; o++) h2[o] = fmaxf(acc2[o], 0.0f);

    // ---- encoder layer 3: 32 -> 4, fast tanh; analytic quantum expvals ----
    // ev_i = prod_{j<=i} cos(enc_j*pi + qp[2j])  (RZ cancels under Z-measure;
    // CNOT chain -> bit i = b0^..^bi; independence factorizes expectation)
    float ev[4];
    float cprod = 1.0f;
    #pragma unroll
    for (int o = 0; o < 4; o++) {
        float acc = eb3[o];
        const float* w = ew3 + o * 32;
        #pragma unroll
        for (int i = 0; i < 32; i++) acc = fmaf(h2[i], w[i], acc);
        // tanh(x) = 1 - 2/(e^{2x}+1); exact at +-inf saturation
        float e = __expf(2.0f * acc);
        float enc = 1.0f - 2.0f / (e + 1.0f);
        float theta = fmaf(enc, 3.14159265358979323846f, qp[2 * o]);
        cprod *= __cosf(theta);
        ev[o] = cprod;
    }

    // ---- decoder layer 1: 4 -> 32, ReLU ----
    float d1[32];
    #pragma unroll 4
    for (int o = 0; o < 32; o++) {
        float acc = db1[o];
        const float* w = dw1 + o * 4;
        #pragma unroll
        for (int i = 0; i < 4; i++) acc = fmaf(ev[i], w[i], acc);
        d1[o] = fmaxf(acc, 0.0f);
    }

    // ---- decoder layer 2: 32 -> 16, ReLU ----
    float d2[16];
    #pragma unroll 4
    for (int o = 0; o < 16; o++) {
        float acc = db2[o];
        const float* w = dw2 + o * 32;
        #pragma unroll
        for (int i = 0; i < 32; i++) acc = fmaf(d1[i], w[i], acc);
        d2[o] = fmaxf(acc, 0.0f);
    }

    // ---- decoder layer 3: 16 -> 8, linear; vectorized store ----
    float o8[8];
    #pragma unroll
    for (int o = 0; o < 8; o++) {
        float acc = db3[o];
        const float* w = dw3 + o * 16;
        #pragma unroll
        for (int i = 0; i < 16; i++) acc = fmaf(d2[i], w[i], acc);
        o8[o] = acc;
    }
    float4* op = (float4*)(out + (b0 + tid) * 8);
    op[0] = make_float4(o8[0], o8[1], o8[2], o8[3]);
    op[1] = make_float4(o8[4], o8[5], o8[6], o8[7]);
}

extern "C" void kernel_launch(void* const* d_in, const int* in_sizes, int n_in,
                              void* d_out, int out_size, void* d_ws, size_t ws_size,
                              hipStream_t stream) {
    const float* state = (const float*)d_in[0];
    const float* ew1 = (const float*)d_in[1];
    const float* eb1 = (const float*)d_in[2];
    const float* ew2 = (const float*)d_in[3];
    const float* eb2 = (const float*)d_in[4];
    const float* ew3 = (const float*)d_in[5];
    const float* eb3 = (const float*)d_in[6];
    const float* qp  = (const float*)d_in[7];
    const float* dw1 = (const float*)d_in[8];
    const float* db1 = (const float*)d_in[9];
    const float* dw2 = (const float*)d_in[10];
    const float* db2 = (const float*)d_in[11];
    const float* dw3 = (const float*)d_in[12];
    const float* db3 = (const float*)d_in[13];
    float* out = (float*)d_out;

    const int B = in_sizes[0] / SD;
    const int grid = (B + BLOCK - 1) / BLOCK;
    hipLaunchKernelGGL(qnet_kernel, dim3(grid), dim3(BLOCK), 0, stream,
                       state, ew1, eb1, ew2, eb2, ew3, eb3, qp,
                       dw1, db1, dw2, db2, dw3, db3, out, B);
}

// Round 9
// 55.474 us; speedup vs baseline: 1.2808x; 1.2808x over previous
//
#include <hip/hip_runtime.h>
#include <math.h>

#define SD 39
#define BLOCK 256

// ---- repacked weight layout in d_ws (float offsets) ----
#define OFF_W1   0      // [64][48]  (39 used, padded)
#define OFF_B1   3072   // [64]
#define OFF_W2T  3136   // [64][32]  transposed: w2t[o1][o2] = ew2[o2*64+o1]
#define OFF_B2   5184   // [32]
#define OFF_W3   5216   // [4][32]
#define OFF_B3   5344   // [4]
#define OFF_QPE  5360   // [4]  qp[0,2,4,6]
#define OFF_DW1  5376   // [32][4]
#define OFF_DB1  5504   // [32]
#define OFF_DW2  5536   // [16][32]
#define OFF_DB2  6048   // [16]
#define OFF_DW3  6064   // [8][16]
#define OFF_DB3  6192   // [8]
#define WS_FLOATS 6200

typedef float vf4 __attribute__((ext_vector_type(4)));

__global__ void repack_kernel(
    const float* __restrict__ ew1, const float* __restrict__ eb1,
    const float* __restrict__ ew2, const float* __restrict__ eb2,
    const float* __restrict__ ew3, const float* __restrict__ eb3,
    const float* __restrict__ qp,
    const float* __restrict__ dw1, const float* __restrict__ db1,
    const float* __restrict__ dw2, const float* __restrict__ db2,
    const float* __restrict__ dw3, const float* __restrict__ db3,
    float* __restrict__ ws)
{
    const int t = threadIdx.x + blockIdx.x * blockDim.x;
    const int stride = blockDim.x * gridDim.x;
    for (int i = t; i < 64 * 48; i += stride) {              // W1 padded
        int o = i / 48, k = i % 48;
        ws[OFF_W1 + i] = (k < SD) ? ew1[o * SD + k] : 0.0f;
    }
    for (int i = t; i < 64; i += stride) ws[OFF_B1 + i] = eb1[i];
    for (int i = t; i < 2048; i += stride) {                 // W2 transposed
        int o1 = i / 32, o2 = i % 32;
        ws[OFF_W2T + i] = ew2[o2 * 64 + o1];
    }
    for (int i = t; i < 32; i += stride)  ws[OFF_B2 + i] = eb2[i];
    for (int i = t; i < 128; i += stride) ws[OFF_W3 + i] = ew3[i];
    for (int i = t; i < 4; i += stride)   ws[OFF_B3 + i] = eb3[i];
    for (int i = t; i < 4; i += stride)   ws[OFF_QPE + i] = qp[2 * i];
    for (int i = t; i < 128; i += stride) ws[OFF_DW1 + i] = dw1[i];
    for (int i = t; i < 32; i += stride)  ws[OFF_DB1 + i] = db1[i];
    for (int i = t; i < 512; i += stride) ws[OFF_DW2 + i] = dw2[i];
    for (int i = t; i < 16; i += stride)  ws[OFF_DB2 + i] = db2[i];
    for (int i = t; i < 128; i += stride) ws[OFF_DW3 + i] = dw3[i];
    for (int i = t; i < 8; i += stride)   ws[OFF_DB3 + i] = db3[i];
}

__global__ __launch_bounds__(BLOCK)
__attribute__((amdgpu_waves_per_eu(1, 4)))
void qnet_kernel(const float* __restrict__ state,
                 const float* __restrict__ wsf,
                 float* __restrict__ out)
{
    const int row = blockIdx.x * BLOCK + threadIdx.x;   // B % 256 == 0: no tail

    // ---- row load: opaque asm, 10x dwordx4, forced to stay in VGPRs ----
    // offsets 0..128 cover floats 0..35; offset 140 covers floats 35..38
    // (exactly ends at byte 156 -> no OOB read on the last row).
    const float* rp = state + (size_t)row * SD;
    vf4 g0, g1, g2, g3, g4, g5, g6, g7, g8, g9;
    asm volatile(
        "global_load_dwordx4 %0, %10, off\n\t"
        "global_load_dwordx4 %1, %10, off offset:16\n\t"
        "global_load_dwordx4 %2, %10, off offset:32\n\t"
        "global_load_dwordx4 %3, %10, off offset:48\n\t"
        "global_load_dwordx4 %4, %10, off offset:64\n\t"
        "global_load_dwordx4 %5, %10, off offset:80\n\t"
        "global_load_dwordx4 %6, %10, off offset:96\n\t"
        "global_load_dwordx4 %7, %10, off offset:112\n\t"
        "global_load_dwordx4 %8, %10, off offset:128\n\t"
        "global_load_dwordx4 %9, %10, off offset:140\n\t"
        "s_waitcnt vmcnt(0)"
        : "=&v"(g0), "=&v"(g1), "=&v"(g2), "=&v"(g3), "=&v"(g4),
          "=&v"(g5), "=&v"(g6), "=&v"(g7), "=&v"(g8), "=&v"(g9)
        : "v"(rp));

    float s[SD];
    #pragma unroll
    for (int j = 0; j < 4; j++) { s[0+j]=g0[j]; s[4+j]=g1[j]; s[8+j]=g2[j];
        s[12+j]=g3[j]; s[16+j]=g4[j]; s[20+j]=g5[j]; s[24+j]=g6[j];
        s[28+j]=g7[j]; s[32+j]=g8[j]; }
    s[36] = g9[1]; s[37] = g9[2]; s[38] = g9[3];

    // ---- FUSED encoder layers 1+2: 39 -> 64 -> 32 ----
    // Weights stream as contiguous wide s_loads from the repacked buffer;
    // w2 is pre-transposed so the o2 inner loop is contiguous.
    float acc2[32];
    #pragma unroll
    for (int o = 0; o < 32; o++) acc2[o] = wsf[OFF_B2 + o];

    #pragma unroll 2
    for (int o1 = 0; o1 < 64; o1++) {
        const float* w1r = wsf + OFF_W1 + o1 * 48;
        float a = wsf[OFF_B1 + o1];
        #pragma unroll
        for (int i = 0; i < SD; i++) a = fmaf(s[i], w1r[i], a);
        a = fmaxf(a, 0.0f);
        const float* w2c = wsf + OFF_W2T + o1 * 32;
        #pragma unroll
        for (int o2 = 0; o2 < 32; o2++)
            acc2[o2] = fmaf(a, w2c[o2], acc2[o2]);
    }

    float h2[32];
    #pragma unroll
    for (int o = 0; o < 32; o++) h2[o] = fmaxf(acc2[o], 0.0f);

    // ---- encoder layer 3: 32 -> 4, fast tanh; analytic quantum expvals ----
    // ev_i = prod_{j<=i} cos(enc_j*pi + qp[2j])  (RZ cancels under Z-measure;
    // CNOT chain -> bit i = b0^..^bi; independence factorizes expectation)
    float ev[4];
    float cprod = 1.0f;
    #pragma unroll
    for (int o = 0; o < 4; o++) {
        const float* w = wsf + OFF_W3 + o * 32;
        float acc = wsf[OFF_B3 + o];
        #pragma unroll
        for (int i = 0; i < 32; i++) acc = fmaf(h2[i], w[i], acc);
        float e = __expf(2.0f * acc);                 // tanh = 1 - 2/(e^{2x}+1)
        float enc = 1.0f - 2.0f / (e + 1.0f);
        float theta = fmaf(enc, 3.14159265358979323846f, wsf[OFF_QPE + o]);
        cprod *= __cosf(theta);
        ev[o] = cprod;
    }

    // ---- decoder ----
    float d1[32];
    #pragma unroll 4
    for (int o = 0; o < 32; o++) {
        const float* w = wsf + OFF_DW1 + o * 4;
        float acc = wsf[OFF_DB1 + o];
        #pragma unroll
        for (int i = 0; i < 4; i++) acc = fmaf(ev[i], w[i], acc);
        d1[o] = fmaxf(acc, 0.0f);
    }
    float d2[16];
    #pragma unroll 4
    for (int o = 0; o < 16; o++) {
        const float* w = wsf + OFF_DW2 + o * 32;
        float acc = wsf[OFF_DB2 + o];
        #pragma unroll
        for (int i = 0; i < 32; i++) acc = fmaf(d1[i], w[i], acc);
        d2[o] = fmaxf(acc, 0.0f);
    }
    float o8[8];
    #pragma unroll
    for (int o = 0; o < 8; o++) {
        const float* w = wsf + OFF_DW3 + o * 16;
        float acc = wsf[OFF_DB3 + o];
        #pragma unroll
        for (int i = 0; i < 16; i++) acc = fmaf(d2[i], w[i], acc);
        o8[o] = acc;
    }

    float4* op = (float4*)(out + (size_t)row * 8);
    op[0] = make_float4(o8[0], o8[1], o8[2], o8[3]);
    op[1] = make_float4(o8[4], o8[5], o8[6], o8[7]);
}

extern "C" void kernel_launch(void* const* d_in, const int* in_sizes, int n_in,
                              void* d_out, int out_size, void* d_ws, size_t ws_size,
                              hipStream_t stream) {
    const float* state = (const float*)d_in[0];
    const float* ew1 = (const float*)d_in[1];
    const float* eb1 = (const float*)d_in[2];
    const float* ew2 = (const float*)d_in[3];
    const float* eb2 = (const float*)d_in[4];
    const float* ew3 = (const float*)d_in[5];
    const float* eb3 = (const float*)d_in[6];
    const float* qp  = (const float*)d_in[7];
    const float* dw1 = (const float*)d_in[8];
    const float* db1 = (const float*)d_in[9];
    const float* dw2 = (const float*)d_in[10];
    const float* db2 = (const float*)d_in[11];
    const float* dw3 = (const float*)d_in[12];
    const float* db3 = (const float*)d_in[13];
    float* out = (float*)d_out;
    float* ws  = (float*)d_ws;

    const int B = in_sizes[0] / SD;

    hipLaunchKernelGGL(repack_kernel, dim3(8), dim3(256), 0, stream,
                       ew1, eb1, ew2, eb2, ew3, eb3, qp,
                       dw1, db1, dw2, db2, dw3, db3, ws);

    const int grid = (B + BLOCK - 1) / BLOCK;
    hipLaunchKernelGGL(qnet_kernel, dim3(grid), dim3(BLOCK), 0, stream,
                       state, ws, out);
}